// Round 2
// baseline (2143.093 us; speedup 1.0000x reference)
//
#include <hip/hip_runtime.h>
#include <stdint.h>

#define N_NODES 50000
#define M_PAD   50048   // 391*128, pad rows never stored (reads of pad are masked at store)
#define NIN     512
#define HDIM    512
#define DDIM    128
#define A_ADJ   3
#define E_EDGES 800000

typedef __bf16 bf16x8 __attribute__((ext_vector_type(8)));
typedef float  f32x4  __attribute__((ext_vector_type(4)));

// ---------------- JAX threefry2x32 (bit-exact) ----------------
__host__ __device__ inline void tf_round(uint32_t& x0, uint32_t& x1, int r) {
  x0 += x1; x1 = (x1 << r) | (x1 >> (32 - r)); x1 ^= x0;
}
__host__ __device__ inline void threefry2x32(uint32_t k0, uint32_t k1,
                                             uint32_t x0, uint32_t x1,
                                             uint32_t& o0, uint32_t& o1) {
  uint32_t ks2 = k0 ^ k1 ^ 0x1BD11BDAu;
  x0 += k0; x1 += k1;
  tf_round(x0,x1,13); tf_round(x0,x1,15); tf_round(x0,x1,26); tf_round(x0,x1,6);
  x0 += k1; x1 += ks2 + 1u;
  tf_round(x0,x1,17); tf_round(x0,x1,29); tf_round(x0,x1,16); tf_round(x0,x1,24);
  x0 += ks2; x1 += k0 + 2u;
  tf_round(x0,x1,13); tf_round(x0,x1,15); tf_round(x0,x1,26); tf_round(x0,x1,6);
  x0 += k0; x1 += k1 + 3u;
  tf_round(x0,x1,17); tf_round(x0,x1,29); tf_round(x0,x1,16); tf_round(x0,x1,24);
  x0 += k1; x1 += ks2 + 4u;
  tf_round(x0,x1,13); tf_round(x0,x1,15); tf_round(x0,x1,26); tf_round(x0,x1,6);
  x0 += ks2; x1 += k0 + 5u;
  o0 = x0; o1 = x1;
}

__device__ inline bool keep_bit(uint32_t b) {
  // jax.random.uniform: bitcast(bits>>9 | 0x3f800000) - 1.0 ; bernoulli: u < 0.8
  float f = __uint_as_float((b >> 9) | 0x3f800000u) - 1.0f;
  return f < 0.8f;
}
__device__ inline uint16_t f2bf(float f) {           // RNE float->bf16
  uint32_t u = __float_as_uint(f);
  return (uint16_t)((u + 0x7fffu + ((u >> 16) & 1u)) >> 16);
}
__device__ inline float bf2f(uint16_t b) { return __uint_as_float(((uint32_t)b) << 16); }

// partitionable-mode 32-bit random bits for flat index i: xor of the two
// threefry output words at counter (hi=0, lo=i)
__device__ inline uint32_t rbits32(uint32_t ka, uint32_t kb, uint32_t i) {
  uint32_t o0, o1;
  threefry2x32(ka, kb, 0u, i, o0, o1);
  return o0 ^ o1;
}

// ---------------- input dropout: seq_a (f32) -> x (bf16) ----------------
__global__ void k_dropin(const float* __restrict__ seq, uint16_t* __restrict__ x,
                         uint32_t ka, uint32_t kb) {
  const int TOT4 = (N_NODES * NIN) / 4;               // 6.4M float4 groups
  int t = blockIdx.x * blockDim.x + threadIdx.x;
  if (t >= TOT4) return;
  int i0 = 4 * t;
  float4 v = ((const float4*)seq)[t];
  float f[4] = {v.x, v.y, v.z, v.w};
  uint16_t r[4];
#pragma unroll
  for (int j = 0; j < 4; ++j) {
    uint32_t bits = rbits32(ka, kb, (uint32_t)(i0 + j));
    r[j] = f2bf(keep_bit(bits) ? f[j] * 1.25f : 0.0f);
  }
  uint2 w;
  w.x = (uint32_t)r[0] | ((uint32_t)r[1] << 16);
  w.y = (uint32_t)r[2] | ((uint32_t)r[3] << 16);
  ((uint2*)x)[t] = w;
}

// ---------------- h_a dropout: h_a (f32, d_out) -> hp0 (bf16) ----------------
__global__ void k_drop2(const float* __restrict__ ha, uint16_t* __restrict__ hp0,
                        uint32_t ka, uint32_t kb) {
  const int TOT4 = (N_NODES * DDIM) / 4;              // 1.6M float4 groups
  int t = blockIdx.x * blockDim.x + threadIdx.x;
  if (t >= TOT4) return;
  int i0 = 4 * t;
  float4 v = ((const float4*)ha)[t];
  float f[4] = {v.x, v.y, v.z, v.w};
  uint16_t r[4];
#pragma unroll
  for (int j = 0; j < 4; ++j) {
    uint32_t bits = rbits32(ka, kb, (uint32_t)(i0 + j));
    r[j] = f2bf(keep_bit(bits) ? f[j] * 1.25f : 0.0f);
  }
  uint2 w;
  w.x = (uint32_t)r[0] | ((uint32_t)r[1] << 16);
  w.y = (uint32_t)r[2] | ((uint32_t)r[3] << 16);
  ((uint2*)hp0)[t] = w;
}

// ---------------- weight transpose + bf16 convert: W[R(k)][C(n)] -> Wt[n][k] ----------------
__global__ void k_transpose(const float* __restrict__ W, uint16_t* __restrict__ Wt,
                            int R, int C) {
  int t = blockIdx.x * blockDim.x + threadIdx.x;      // over R*C/2
  if (t >= (R * C) / 2) return;
  int k2 = (2 * t) % R;
  int n  = (2 * t) / R;
  uint32_t p = (uint32_t)f2bf(W[(size_t)k2 * C + n])
             | ((uint32_t)f2bf(W[(size_t)(k2 + 1) * C + n]) << 16);
  *(uint32_t*)&Wt[(size_t)n * R + k2] = p;
}

// ---------------- GEMM: C[M][Nn] = A[M][K](bf16) @ Bt[Nn][K](bf16)^T + bias ----------------
// MODE 0: relu -> bf16 out (h).  MODE 1: f32 out (h_a).
template <int MODE>
__global__ __launch_bounds__(256) void k_gemm(const uint16_t* __restrict__ A,
                                              const uint16_t* __restrict__ Bt,
                                              const float* __restrict__ bias,
                                              uint16_t* __restrict__ hOut,
                                              float* __restrict__ fOut,
                                              int Nn, int K) {
  __shared__ __align__(16) uint16_t As[128 * 32];
  __shared__ __align__(16) uint16_t Bs[128 * 32];
  const int t  = threadIdx.x;
  const int w  = t >> 6, l = t & 63;
  const int lm = l & 15, kg = l >> 4;
  const int wr = w >> 1, wc = w & 1;
  const int rowbase = blockIdx.y * 128;
  const int colbase = blockIdx.x * 128;
  const int c0 = t, c1 = t + 256;                     // 16B chunks (8 bf16) of an 8KB tile

  f32x4 acc[4][4] = {};

  for (int kt = 0; kt < K; kt += 32) {
    uint4 va0 = *(const uint4*)&A [(size_t)(rowbase + (c0 >> 2)) * K + kt + (c0 & 3) * 8];
    uint4 va1 = *(const uint4*)&A [(size_t)(rowbase + (c1 >> 2)) * K + kt + (c1 & 3) * 8];
    uint4 vb0 = *(const uint4*)&Bt[(size_t)(colbase + (c0 >> 2)) * K + kt + (c0 & 3) * 8];
    uint4 vb1 = *(const uint4*)&Bt[(size_t)(colbase + (c1 >> 2)) * K + kt + (c1 & 3) * 8];
    __syncthreads();                                  // previous compute done
    *(uint4*)&As[c0 * 8] = va0;
    *(uint4*)&As[c1 * 8] = va1;
    *(uint4*)&Bs[c0 * 8] = vb0;
    *(uint4*)&Bs[c1 * 8] = vb1;
    __syncthreads();                                  // tile ready

    bf16x8 af[4], bfr[4];
#pragma unroll
    for (int m = 0; m < 4; ++m)
      af[m] = *(const bf16x8*)&As[(wr * 64 + m * 16 + lm) * 32 + kg * 8];
#pragma unroll
    for (int n = 0; n < 4; ++n)
      bfr[n] = *(const bf16x8*)&Bs[(wc * 64 + n * 16 + lm) * 32 + kg * 8];
#pragma unroll
    for (int m = 0; m < 4; ++m)
#pragma unroll
      for (int n = 0; n < 4; ++n)
        acc[m][n] = __builtin_amdgcn_mfma_f32_16x16x32_bf16(af[m], bfr[n], acc[m][n], 0, 0, 0);
  }

#pragma unroll
  for (int m = 0; m < 4; ++m) {
    int r0 = rowbase + wr * 64 + m * 16 + kg * 4;     // C/D: row=(l>>4)*4+reg, col=l&15
#pragma unroll
    for (int n = 0; n < 4; ++n) {
      int cc = colbase + wc * 64 + n * 16 + lm;
      float bv = bias[cc];
#pragma unroll
      for (int r = 0; r < 4; ++r) {
        int row = r0 + r;
        if (row < N_NODES) {
          float v = acc[m][n][r] + bv;
          if (MODE == 0) hOut[(size_t)row * Nn + cc] = f2bf(fmaxf(v, 0.0f));
          else           fOut[(size_t)row * Nn + cc] = v;
        }
      }
    }
  }
}

// ---------------- SpMM: one wave per edge, 2 f32 atomics per lane ----------------
__global__ void k_spmm(const int* __restrict__ rows, const int* __restrict__ cols,
                       const float* __restrict__ vals, const uint16_t* __restrict__ hp0,
                       float* __restrict__ stack) {
  int gw = (int)((blockIdx.x * (size_t)blockDim.x + threadIdx.x) >> 6);
  int l  = threadIdx.x & 63;
  if (gw >= A_ADJ * E_EDGES) return;
  int a = gw / E_EDGES;
  int row = rows[gw], col = cols[gw];
  float v = vals[gw];
  uint32_t p = ((const uint32_t*)hp0)[(size_t)col * (DDIM / 2) + l];
  float x0 = bf2f((uint16_t)(p & 0xffffu)) * v;
  float x1 = bf2f((uint16_t)(p >> 16)) * v;
  float* dst = stack + ((size_t)a * N_NODES + row) * DDIM + l * 2;
  atomicAdd(dst, x0);
  atomicAdd(dst + 1, x1);
}

// ---------------- fusion: mean over A ----------------
__global__ void k_fusion(const float* __restrict__ stack, float* __restrict__ fus) {
  const int Q = (N_NODES * DDIM) / 4;                 // 1.6M float4
  int t = blockIdx.x * blockDim.x + threadIdx.x;
  if (t >= Q) return;
  const float4* s = (const float4*)stack;
  float4 s0 = s[t], s1 = s[t + Q], s2 = s[t + 2 * Q];
  float4 r;
  r.x = (s0.x + s1.x + s2.x) * (1.0f / 3.0f);
  r.y = (s0.y + s1.y + s2.y) * (1.0f / 3.0f);
  r.z = (s0.z + s1.z + s2.z) * (1.0f / 3.0f);
  r.w = (s0.w + s1.w + s2.w) * (1.0f / 3.0f);
  ((float4*)fus)[t] = r;
}

extern "C" void kernel_launch(void* const* d_in, const int* in_sizes, int n_in,
                              void* d_out, int out_size, void* d_ws, size_t ws_size,
                              hipStream_t stream) {
  const float* seq  = (const float*)d_in[0];
  const float* W1   = (const float*)d_in[1];
  const float* b1   = (const float*)d_in[2];
  const float* W2   = (const float*)d_in[3];
  const float* b2   = (const float*)d_in[4];
  const float* vals = (const float*)d_in[5];
  const int*   rows = (const int*)d_in[6];
  const int*   cols = (const int*)d_in[7];

  float* out       = (float*)d_out;
  float* out_ha    = out;                                       // [N, D]
  float* out_stack = out + (size_t)N_NODES * DDIM;              // [A, N, D]
  float* out_fus   = out_stack + (size_t)A_ADJ * N_NODES * DDIM;

  uint16_t* x   = (uint16_t*)d_ws;                              // [M_PAD, NIN] bf16
  uint16_t* h   = x   + (size_t)M_PAD * NIN;                    // [M_PAD, HDIM] bf16
  uint16_t* w1t = h   + (size_t)M_PAD * HDIM;                   // [HDIM, NIN]  bf16 (W1^T)
  uint16_t* w2t = w1t + (size_t)HDIM * NIN;                     // [DDIM, HDIM] bf16 (W2^T)
  uint16_t* hp0 = w2t + (size_t)DDIM * HDIM;                    // [N, D] bf16

  // JAX partitionable-mode split of key (0,42):
  //   k_j = full threefry2x32 output pair at counter (hi=0, lo=j)
  uint32_t k0a, k0b, k1a, k1b;
  threefry2x32(0u, 42u, 0u, 0u, k0a, k0b);
  threefry2x32(0u, 42u, 0u, 1u, k1a, k1b);

  (void)hipMemsetAsync(out_stack, 0, (size_t)A_ADJ * N_NODES * DDIM * sizeof(float), stream);

  k_transpose<<<(HDIM * NIN / 2 + 255) / 256, 256, 0, stream>>>(W1, w1t, NIN, HDIM);
  k_transpose<<<(HDIM * DDIM / 2 + 255) / 256, 256, 0, stream>>>(W2, w2t, HDIM, DDIM);

  k_dropin<<<((N_NODES * NIN / 4) + 255) / 256, 256, 0, stream>>>(seq, x, k0a, k0b);

  dim3 g1(HDIM / 128, M_PAD / 128);   // (4, 391)
  k_gemm<0><<<g1, 256, 0, stream>>>(x, w1t, b1, h, nullptr, HDIM, NIN);

  dim3 g2(DDIM / 128, M_PAD / 128);   // (1, 391)
  k_gemm<1><<<g2, 256, 0, stream>>>(h, w2t, b2, nullptr, out_ha, DDIM, HDIM);

  k_drop2<<<((N_NODES * DDIM / 4) + 255) / 256, 256, 0, stream>>>(out_ha, hp0, k1a, k1b);

  size_t spmm_threads = (size_t)A_ADJ * E_EDGES * 64;
  k_spmm<<<(unsigned)((spmm_threads + 255) / 256), 256, 0, stream>>>(rows, cols, vals, hp0, out_stack);

  k_fusion<<<((N_NODES * DDIM / 4) + 255) / 256, 256, 0, stream>>>(out_stack, out_fus);
}

// Round 3
// 881.870 us; speedup vs baseline: 2.4302x; 2.4302x over previous
//
#include <hip/hip_runtime.h>
#include <stdint.h>

#define N_NODES 50000
#define M_PAD   50048   // 391*128, pad rows never stored (reads of pad are masked at store)
#define NIN     512
#define HDIM    512
#define DDIM    128
#define A_ADJ   3
#define E_EDGES 800000

typedef __bf16 bf16x8 __attribute__((ext_vector_type(8)));
typedef float  f32x4  __attribute__((ext_vector_type(4)));

// ---------------- JAX threefry2x32 (bit-exact, partitionable mode) ----------------
__host__ __device__ inline void tf_round(uint32_t& x0, uint32_t& x1, int r) {
  x0 += x1; x1 = (x1 << r) | (x1 >> (32 - r)); x1 ^= x0;
}
__host__ __device__ inline void threefry2x32(uint32_t k0, uint32_t k1,
                                             uint32_t x0, uint32_t x1,
                                             uint32_t& o0, uint32_t& o1) {
  uint32_t ks2 = k0 ^ k1 ^ 0x1BD11BDAu;
  x0 += k0; x1 += k1;
  tf_round(x0,x1,13); tf_round(x0,x1,15); tf_round(x0,x1,26); tf_round(x0,x1,6);
  x0 += k1; x1 += ks2 + 1u;
  tf_round(x0,x1,17); tf_round(x0,x1,29); tf_round(x0,x1,16); tf_round(x0,x1,24);
  x0 += ks2; x1 += k0 + 2u;
  tf_round(x0,x1,13); tf_round(x0,x1,15); tf_round(x0,x1,26); tf_round(x0,x1,6);
  x0 += k0; x1 += k1 + 3u;
  tf_round(x0,x1,17); tf_round(x0,x1,29); tf_round(x0,x1,16); tf_round(x0,x1,24);
  x0 += k1; x1 += ks2 + 4u;
  tf_round(x0,x1,13); tf_round(x0,x1,15); tf_round(x0,x1,26); tf_round(x0,x1,6);
  x0 += ks2; x1 += k0 + 5u;
  o0 = x0; o1 = x1;
}

__device__ inline bool keep_bit(uint32_t b) {
  float f = __uint_as_float((b >> 9) | 0x3f800000u) - 1.0f;
  return f < 0.8f;
}
__device__ inline uint16_t f2bf(float f) {           // RNE float->bf16
  uint32_t u = __float_as_uint(f);
  return (uint16_t)((u + 0x7fffu + ((u >> 16) & 1u)) >> 16);
}
__device__ inline float bf2f(uint16_t b) { return __uint_as_float(((uint32_t)b) << 16); }

__device__ inline uint32_t rbits32(uint32_t ka, uint32_t kb, uint32_t i) {
  uint32_t o0, o1;
  threefry2x32(ka, kb, 0u, i, o0, o1);
  return o0 ^ o1;
}

// ---------------- input dropout: seq_a (f32) -> x (bf16) ----------------
__global__ void k_dropin(const float* __restrict__ seq, uint16_t* __restrict__ x,
                         uint32_t ka, uint32_t kb) {
  const int TOT4 = (N_NODES * NIN) / 4;
  int t = blockIdx.x * blockDim.x + threadIdx.x;
  if (t >= TOT4) return;
  int i0 = 4 * t;
  float4 v = ((const float4*)seq)[t];
  float f[4] = {v.x, v.y, v.z, v.w};
  uint16_t r[4];
#pragma unroll
  for (int j = 0; j < 4; ++j) {
    uint32_t bits = rbits32(ka, kb, (uint32_t)(i0 + j));
    r[j] = f2bf(keep_bit(bits) ? f[j] * 1.25f : 0.0f);
  }
  uint2 w;
  w.x = (uint32_t)r[0] | ((uint32_t)r[1] << 16);
  w.y = (uint32_t)r[2] | ((uint32_t)r[3] << 16);
  ((uint2*)x)[t] = w;
}

// ---------------- h_a dropout: h_a (f32, d_out) -> hp0 (bf16) ----------------
__global__ void k_drop2(const float* __restrict__ ha, uint16_t* __restrict__ hp0,
                        uint32_t ka, uint32_t kb) {
  const int TOT4 = (N_NODES * DDIM) / 4;
  int t = blockIdx.x * blockDim.x + threadIdx.x;
  if (t >= TOT4) return;
  int i0 = 4 * t;
  float4 v = ((const float4*)ha)[t];
  float f[4] = {v.x, v.y, v.z, v.w};
  uint16_t r[4];
#pragma unroll
  for (int j = 0; j < 4; ++j) {
    uint32_t bits = rbits32(ka, kb, (uint32_t)(i0 + j));
    r[j] = f2bf(keep_bit(bits) ? f[j] * 1.25f : 0.0f);
  }
  uint2 w;
  w.x = (uint32_t)r[0] | ((uint32_t)r[1] << 16);
  w.y = (uint32_t)r[2] | ((uint32_t)r[3] << 16);
  ((uint2*)hp0)[t] = w;
}

// ---------------- weight transpose + bf16 convert ----------------
__global__ void k_transpose(const float* __restrict__ W, uint16_t* __restrict__ Wt,
                            int R, int C) {
  int t = blockIdx.x * blockDim.x + threadIdx.x;
  if (t >= (R * C) / 2) return;
  int k2 = (2 * t) % R;
  int n  = (2 * t) / R;
  uint32_t p = (uint32_t)f2bf(W[(size_t)k2 * C + n])
             | ((uint32_t)f2bf(W[(size_t)(k2 + 1) * C + n]) << 16);
  *(uint32_t*)&Wt[(size_t)n * R + k2] = p;
}

// ---------------- GEMM (unchanged from round 2) ----------------
template <int MODE>
__global__ __launch_bounds__(256) void k_gemm(const uint16_t* __restrict__ A,
                                              const uint16_t* __restrict__ Bt,
                                              const float* __restrict__ bias,
                                              uint16_t* __restrict__ hOut,
                                              float* __restrict__ fOut,
                                              int Nn, int K) {
  __shared__ __align__(16) uint16_t As[128 * 32];
  __shared__ __align__(16) uint16_t Bs[128 * 32];
  const int t  = threadIdx.x;
  const int w  = t >> 6, l = t & 63;
  const int lm = l & 15, kg = l >> 4;
  const int wr = w >> 1, wc = w & 1;
  const int rowbase = blockIdx.y * 128;
  const int colbase = blockIdx.x * 128;
  const int c0 = t, c1 = t + 256;

  f32x4 acc[4][4] = {};

  for (int kt = 0; kt < K; kt += 32) {
    uint4 va0 = *(const uint4*)&A [(size_t)(rowbase + (c0 >> 2)) * K + kt + (c0 & 3) * 8];
    uint4 va1 = *(const uint4*)&A [(size_t)(rowbase + (c1 >> 2)) * K + kt + (c1 & 3) * 8];
    uint4 vb0 = *(const uint4*)&Bt[(size_t)(colbase + (c0 >> 2)) * K + kt + (c0 & 3) * 8];
    uint4 vb1 = *(const uint4*)&Bt[(size_t)(colbase + (c1 >> 2)) * K + kt + (c1 & 3) * 8];
    __syncthreads();
    *(uint4*)&As[c0 * 8] = va0;
    *(uint4*)&As[c1 * 8] = va1;
    *(uint4*)&Bs[c0 * 8] = vb0;
    *(uint4*)&Bs[c1 * 8] = vb1;
    __syncthreads();

    bf16x8 af[4], bfr[4];
#pragma unroll
    for (int m = 0; m < 4; ++m)
      af[m] = *(const bf16x8*)&As[(wr * 64 + m * 16 + lm) * 32 + kg * 8];
#pragma unroll
    for (int n = 0; n < 4; ++n)
      bfr[n] = *(const bf16x8*)&Bs[(wc * 64 + n * 16 + lm) * 32 + kg * 8];
#pragma unroll
    for (int m = 0; m < 4; ++m)
#pragma unroll
      for (int n = 0; n < 4; ++n)
        acc[m][n] = __builtin_amdgcn_mfma_f32_16x16x32_bf16(af[m], bfr[n], acc[m][n], 0, 0, 0);
  }

#pragma unroll
  for (int m = 0; m < 4; ++m) {
    int r0 = rowbase + wr * 64 + m * 16 + kg * 4;
#pragma unroll
    for (int n = 0; n < 4; ++n) {
      int cc = colbase + wc * 64 + n * 16 + lm;
      float bv = bias[cc];
#pragma unroll
      for (int r = 0; r < 4; ++r) {
        int row = r0 + r;
        if (row < N_NODES) {
          float v = acc[m][n][r] + bv;
          if (MODE == 0) hOut[(size_t)row * Nn + cc] = f2bf(fmaxf(v, 0.0f));
          else           fOut[(size_t)row * Nn + cc] = v;
        }
      }
    }
  }
}

// ---------------- CSR build: histogram / scan / scatter ----------------
__global__ void k_hist(const int* __restrict__ rows, uint32_t* __restrict__ counts) {
  int t = blockIdx.x * blockDim.x + threadIdx.x;      // over A*E
  if (t >= A_ADJ * E_EDGES) return;
  int a = t / E_EDGES;
  atomicAdd(&counts[a * N_NODES + rows[t]], 1u);
}

#define SCAN_T 1024
__global__ __launch_bounds__(SCAN_T) void k_scan(const uint32_t* __restrict__ counts,
                                                 uint32_t* __restrict__ offs) {
  // exclusive scan of A*N counts -> offs[0..A*N-1]; offs[A*N] = total
  __shared__ uint32_t sums[SCAN_T];
  const int TOT = A_ADJ * N_NODES;                    // 150000
  int t = threadIdx.x;
  const int per = (TOT + SCAN_T - 1) / SCAN_T;        // 147
  int lo = t * per, hi = lo + per; if (hi > TOT) hi = TOT;
  uint32_t s = 0;
  for (int i = lo; i < hi; ++i) s += counts[i];
  sums[t] = s;
  __syncthreads();
  for (int off = 1; off < SCAN_T; off <<= 1) {
    uint32_t v = (t >= off) ? sums[t - off] : 0u;
    __syncthreads();
    sums[t] += v;
    __syncthreads();
  }
  uint32_t run = (t == 0) ? 0u : sums[t - 1];
  for (int i = lo; i < hi; ++i) { offs[i] = run; run += counts[i]; }
  if (t == SCAN_T - 1) offs[TOT] = sums[SCAN_T - 1];
}

__global__ void k_scatter(const int* __restrict__ rows, const int* __restrict__ cols,
                          const float* __restrict__ vals, uint32_t* __restrict__ cursor,
                          uint64_t* __restrict__ sedge) {
  int t = blockIdx.x * blockDim.x + threadIdx.x;      // over A*E
  if (t >= A_ADJ * E_EDGES) return;
  int a = t / E_EDGES;
  uint32_t pos = atomicAdd(&cursor[a * N_NODES + rows[t]], 1u);
  uint64_t packed = ((uint64_t)__float_as_uint(vals[t]) << 32) | (uint32_t)cols[t];
  sedge[pos] = packed;
}

// ---------------- SpMM over CSR: one wave per (a,row), no atomics ----------------
__global__ void k_spmm_csr(const uint32_t* __restrict__ offs,
                           const uint64_t* __restrict__ sedge,
                           const uint16_t* __restrict__ hp0,
                           float* __restrict__ stack) {
  int gw = (int)((blockIdx.x * (size_t)blockDim.x + threadIdx.x) >> 6);  // (a*N+row)
  int l = threadIdx.x & 63;
  if (gw >= A_ADJ * N_NODES) return;
  uint32_t s = offs[gw], e = offs[gw + 1];
  float a0 = 0.0f, a1 = 0.0f;
  const uint32_t* hp32 = (const uint32_t*)hp0;
  for (uint32_t i = s; i < e; ++i) {
    uint64_t ed = sedge[i];
    uint32_t col = (uint32_t)ed;
    float v = __uint_as_float((uint32_t)(ed >> 32));
    uint32_t p = hp32[(size_t)col * 64 + l];
    a0 += bf2f((uint16_t)(p & 0xffffu)) * v;
    a1 += bf2f((uint16_t)(p >> 16)) * v;
  }
  ((float2*)stack)[(size_t)gw * 64 + l] = make_float2(a0, a1);
}

// ---------------- fusion: mean over A ----------------
__global__ void k_fusion(const float* __restrict__ stack, float* __restrict__ fus) {
  const int Q = (N_NODES * DDIM) / 4;
  int t = blockIdx.x * blockDim.x + threadIdx.x;
  if (t >= Q) return;
  const float4* s = (const float4*)stack;
  float4 s0 = s[t], s1 = s[t + Q], s2 = s[t + 2 * Q];
  float4 r;
  r.x = (s0.x + s1.x + s2.x) * (1.0f / 3.0f);
  r.y = (s0.y + s1.y + s2.y) * (1.0f / 3.0f);
  r.z = (s0.z + s1.z + s2.z) * (1.0f / 3.0f);
  r.w = (s0.w + s1.w + s2.w) * (1.0f / 3.0f);
  ((float4*)fus)[t] = r;
}

extern "C" void kernel_launch(void* const* d_in, const int* in_sizes, int n_in,
                              void* d_out, int out_size, void* d_ws, size_t ws_size,
                              hipStream_t stream) {
  const float* seq  = (const float*)d_in[0];
  const float* W1   = (const float*)d_in[1];
  const float* b1   = (const float*)d_in[2];
  const float* W2   = (const float*)d_in[3];
  const float* b2   = (const float*)d_in[4];
  const float* vals = (const float*)d_in[5];
  const int*   rows = (const int*)d_in[6];
  const int*   cols = (const int*)d_in[7];

  float* out       = (float*)d_out;
  float* out_ha    = out;                                       // [N, D]
  float* out_stack = out + (size_t)N_NODES * DDIM;              // [A, N, D]
  float* out_fus   = out_stack + (size_t)A_ADJ * N_NODES * DDIM;

  uint16_t* x   = (uint16_t*)d_ws;                              // [M_PAD, NIN] bf16
  uint16_t* h   = x   + (size_t)M_PAD * NIN;                    // [M_PAD, HDIM] bf16
  uint16_t* w1t = h   + (size_t)M_PAD * HDIM;                   // [HDIM, NIN]  bf16
  uint16_t* w2t = w1t + (size_t)HDIM * NIN;                     // [DDIM, HDIM] bf16
  uint16_t* hp0 = w2t + (size_t)DDIM * HDIM;                    // [N, D] bf16

  // CSR-build buffers alias the x region (x is dead after k_gemm<0>)
  char* xbase = (char*)d_ws;
  uint32_t* counts = (uint32_t*)(xbase);                        // [A*N]
  uint32_t* offs   = (uint32_t*)(xbase + 640 * 1024);           // [A*N + 1]
  uint32_t* cursor = (uint32_t*)(xbase + 1280 * 1024);          // [A*N]
  uint64_t* sedge  = (uint64_t*)(xbase + 2048 * 1024);          // [A*E] (19.2 MB)

  // JAX partitionable-mode split of key (0,42)
  uint32_t k0a, k0b, k1a, k1b;
  threefry2x32(0u, 42u, 0u, 0u, k0a, k0b);
  threefry2x32(0u, 42u, 0u, 1u, k1a, k1b);

  k_transpose<<<(HDIM * NIN / 2 + 255) / 256, 256, 0, stream>>>(W1, w1t, NIN, HDIM);
  k_transpose<<<(HDIM * DDIM / 2 + 255) / 256, 256, 0, stream>>>(W2, w2t, HDIM, DDIM);

  k_dropin<<<((N_NODES * NIN / 4) + 255) / 256, 256, 0, stream>>>(seq, x, k0a, k0b);

  dim3 g1(HDIM / 128, M_PAD / 128);   // (4, 391)
  k_gemm<0><<<g1, 256, 0, stream>>>(x, w1t, b1, h, nullptr, HDIM, NIN);

  // ---- CSR build (x region now dead) ----
  (void)hipMemsetAsync(counts, 0, (size_t)A_ADJ * N_NODES * sizeof(uint32_t), stream);
  k_hist<<<(A_ADJ * E_EDGES + 255) / 256, 256, 0, stream>>>(rows, counts);
  k_scan<<<1, SCAN_T, 0, stream>>>(counts, offs);
  (void)hipMemcpyAsync(cursor, offs, (size_t)A_ADJ * N_NODES * sizeof(uint32_t),
                       hipMemcpyDeviceToDevice, stream);
  k_scatter<<<(A_ADJ * E_EDGES + 255) / 256, 256, 0, stream>>>(rows, cols, vals, cursor, sedge);

  dim3 g2(DDIM / 128, M_PAD / 128);   // (1, 391)
  k_gemm<1><<<g2, 256, 0, stream>>>(h, w2t, b2, nullptr, out_ha, DDIM, HDIM);

  k_drop2<<<((N_NODES * DDIM / 4) + 255) / 256, 256, 0, stream>>>(out_ha, hp0, k1a, k1b);

  size_t csr_threads = (size_t)A_ADJ * N_NODES * 64;
  k_spmm_csr<<<(unsigned)((csr_threads + 255) / 256), 256, 0, stream>>>(offs, sedge, hp0, out_stack);

  k_fusion<<<((N_NODES * DDIM / 4) + 255) / 256, 256, 0, stream>>>(out_stack, out_fus);
}

// Round 4
// 599.864 us; speedup vs baseline: 3.5726x; 1.4701x over previous
//
#include <hip/hip_runtime.h>
#include <stdint.h>

#define N_NODES 50000
#define M_PAD   50048   // 391*128, pad rows never stored (reads of pad are masked at store)
#define NIN     512
#define HDIM    512
#define DDIM    128
#define A_ADJ   3
#define E_EDGES 800000
#define TOT_ROWS (A_ADJ * N_NODES)          // 150000
#define NSCB     147                        // ceil(150000/1024) scan blocks

typedef __bf16 bf16x8 __attribute__((ext_vector_type(8)));
typedef float  f32x4  __attribute__((ext_vector_type(4)));

// ---------------- JAX threefry2x32 (bit-exact, partitionable mode) ----------------
__host__ __device__ inline void tf_round(uint32_t& x0, uint32_t& x1, int r) {
  x0 += x1; x1 = (x1 << r) | (x1 >> (32 - r)); x1 ^= x0;
}
__host__ __device__ inline void threefry2x32(uint32_t k0, uint32_t k1,
                                             uint32_t x0, uint32_t x1,
                                             uint32_t& o0, uint32_t& o1) {
  uint32_t ks2 = k0 ^ k1 ^ 0x1BD11BDAu;
  x0 += k0; x1 += k1;
  tf_round(x0,x1,13); tf_round(x0,x1,15); tf_round(x0,x1,26); tf_round(x0,x1,6);
  x0 += k1; x1 += ks2 + 1u;
  tf_round(x0,x1,17); tf_round(x0,x1,29); tf_round(x0,x1,16); tf_round(x0,x1,24);
  x0 += ks2; x1 += k0 + 2u;
  tf_round(x0,x1,13); tf_round(x0,x1,15); tf_round(x0,x1,26); tf_round(x0,x1,6);
  x0 += k0; x1 += k1 + 3u;
  tf_round(x0,x1,17); tf_round(x0,x1,29); tf_round(x0,x1,16); tf_round(x0,x1,24);
  x0 += k1; x1 += ks2 + 4u;
  tf_round(x0,x1,13); tf_round(x0,x1,15); tf_round(x0,x1,26); tf_round(x0,x1,6);
  x0 += ks2; x1 += k0 + 5u;
  o0 = x0; o1 = x1;
}

__device__ inline bool keep_bit(uint32_t b) {
  float f = __uint_as_float((b >> 9) | 0x3f800000u) - 1.0f;
  return f < 0.8f;
}
__device__ inline uint16_t f2bf(float f) {           // RNE float->bf16
  uint32_t u = __float_as_uint(f);
  return (uint16_t)((u + 0x7fffu + ((u >> 16) & 1u)) >> 16);
}
__device__ inline float bf2f(uint16_t b) { return __uint_as_float(((uint32_t)b) << 16); }

__device__ inline uint32_t rbits32(uint32_t ka, uint32_t kb, uint32_t i) {
  uint32_t o0, o1;
  threefry2x32(ka, kb, 0u, i, o0, o1);
  return o0 ^ o1;
}

// ---------------- input dropout: seq_a (f32) -> x (bf16) ----------------
__global__ void k_dropin(const float* __restrict__ seq, uint16_t* __restrict__ x,
                         uint32_t ka, uint32_t kb) {
  const int TOT4 = (N_NODES * NIN) / 4;
  int t = blockIdx.x * blockDim.x + threadIdx.x;
  if (t >= TOT4) return;
  int i0 = 4 * t;
  float4 v = ((const float4*)seq)[t];
  float f[4] = {v.x, v.y, v.z, v.w};
  uint16_t r[4];
#pragma unroll
  for (int j = 0; j < 4; ++j) {
    uint32_t bits = rbits32(ka, kb, (uint32_t)(i0 + j));
    r[j] = f2bf(keep_bit(bits) ? f[j] * 1.25f : 0.0f);
  }
  uint2 w;
  w.x = (uint32_t)r[0] | ((uint32_t)r[1] << 16);
  w.y = (uint32_t)r[2] | ((uint32_t)r[3] << 16);
  ((uint2*)x)[t] = w;
}

// ---------------- h_a dropout: h_a (f32, d_out) -> hp0 (bf16) ----------------
__global__ void k_drop2(const float* __restrict__ ha, uint16_t* __restrict__ hp0,
                        uint32_t ka, uint32_t kb) {
  const int TOT4 = (N_NODES * DDIM) / 4;
  int t = blockIdx.x * blockDim.x + threadIdx.x;
  if (t >= TOT4) return;
  int i0 = 4 * t;
  float4 v = ((const float4*)ha)[t];
  float f[4] = {v.x, v.y, v.z, v.w};
  uint16_t r[4];
#pragma unroll
  for (int j = 0; j < 4; ++j) {
    uint32_t bits = rbits32(ka, kb, (uint32_t)(i0 + j));
    r[j] = f2bf(keep_bit(bits) ? f[j] * 1.25f : 0.0f);
  }
  uint2 w;
  w.x = (uint32_t)r[0] | ((uint32_t)r[1] << 16);
  w.y = (uint32_t)r[2] | ((uint32_t)r[3] << 16);
  ((uint2*)hp0)[t] = w;
}

// ---------------- weight transpose + bf16 convert ----------------
__global__ void k_transpose(const float* __restrict__ W, uint16_t* __restrict__ Wt,
                            int R, int C) {
  int t = blockIdx.x * blockDim.x + threadIdx.x;
  if (t >= (R * C) / 2) return;
  int k2 = (2 * t) % R;
  int n  = (2 * t) / R;
  uint32_t p = (uint32_t)f2bf(W[(size_t)k2 * C + n])
             | ((uint32_t)f2bf(W[(size_t)(k2 + 1) * C + n]) << 16);
  *(uint32_t*)&Wt[(size_t)n * R + k2] = p;
}

// ---------------- GEMM (unchanged) ----------------
template <int MODE>
__global__ __launch_bounds__(256) void k_gemm(const uint16_t* __restrict__ A,
                                              const uint16_t* __restrict__ Bt,
                                              const float* __restrict__ bias,
                                              uint16_t* __restrict__ hOut,
                                              float* __restrict__ fOut,
                                              int Nn, int K) {
  __shared__ __align__(16) uint16_t As[128 * 32];
  __shared__ __align__(16) uint16_t Bs[128 * 32];
  const int t  = threadIdx.x;
  const int w  = t >> 6, l = t & 63;
  const int lm = l & 15, kg = l >> 4;
  const int wr = w >> 1, wc = w & 1;
  const int rowbase = blockIdx.y * 128;
  const int colbase = blockIdx.x * 128;
  const int c0 = t, c1 = t + 256;

  f32x4 acc[4][4] = {};

  for (int kt = 0; kt < K; kt += 32) {
    uint4 va0 = *(const uint4*)&A [(size_t)(rowbase + (c0 >> 2)) * K + kt + (c0 & 3) * 8];
    uint4 va1 = *(const uint4*)&A [(size_t)(rowbase + (c1 >> 2)) * K + kt + (c1 & 3) * 8];
    uint4 vb0 = *(const uint4*)&Bt[(size_t)(colbase + (c0 >> 2)) * K + kt + (c0 & 3) * 8];
    uint4 vb1 = *(const uint4*)&Bt[(size_t)(colbase + (c1 >> 2)) * K + kt + (c1 & 3) * 8];
    __syncthreads();
    *(uint4*)&As[c0 * 8] = va0;
    *(uint4*)&As[c1 * 8] = va1;
    *(uint4*)&Bs[c0 * 8] = vb0;
    *(uint4*)&Bs[c1 * 8] = vb1;
    __syncthreads();

    bf16x8 af[4], bfr[4];
#pragma unroll
    for (int m = 0; m < 4; ++m)
      af[m] = *(const bf16x8*)&As[(wr * 64 + m * 16 + lm) * 32 + kg * 8];
#pragma unroll
    for (int n = 0; n < 4; ++n)
      bfr[n] = *(const bf16x8*)&Bs[(wc * 64 + n * 16 + lm) * 32 + kg * 8];
#pragma unroll
    for (int m = 0; m < 4; ++m)
#pragma unroll
      for (int n = 0; n < 4; ++n)
        acc[m][n] = __builtin_amdgcn_mfma_f32_16x16x32_bf16(af[m], bfr[n], acc[m][n], 0, 0, 0);
  }

#pragma unroll
  for (int m = 0; m < 4; ++m) {
    int r0 = rowbase + wr * 64 + m * 16 + kg * 4;
#pragma unroll
    for (int n = 0; n < 4; ++n) {
      int cc = colbase + wc * 64 + n * 16 + lm;
      float bv = bias[cc];
#pragma unroll
      for (int r = 0; r < 4; ++r) {
        int row = r0 + r;
        if (row < N_NODES) {
          float v = acc[m][n][r] + bv;
          if (MODE == 0) hOut[(size_t)row * Nn + cc] = f2bf(fmaxf(v, 0.0f));
          else           fOut[(size_t)row * Nn + cc] = v;
        }
      }
    }
  }
}

// ---------------- CSR build: histogram / hierarchical scan / scatter ----------------
__global__ void k_hist(const int* __restrict__ rows, uint32_t* __restrict__ counts) {
  int t = blockIdx.x * blockDim.x + threadIdx.x;      // over A*E
  if (t >= A_ADJ * E_EDGES) return;
  int a = t / E_EDGES;
  atomicAdd(&counts[a * N_NODES + rows[t]], 1u);
}

// level 1: each block scans 1024 counts (256 thr x 4), writes per-elem exclusive
// offsets (block-local) and its block total.
__global__ __launch_bounds__(256) void k_scan1(const uint32_t* __restrict__ counts,
                                               uint32_t* __restrict__ offs_local,
                                               uint32_t* __restrict__ blocksums) {
  __shared__ uint32_t tsum[256];
  int b = blockIdx.x, t = threadIdx.x;
  int base = b * 1024 + t * 4;
  uint32_t c[4];
#pragma unroll
  for (int j = 0; j < 4; ++j) c[j] = (base + j < TOT_ROWS) ? counts[base + j] : 0u;
  uint32_t s = c[0] + c[1] + c[2] + c[3];
  tsum[t] = s;
  __syncthreads();
  uint32_t own = s;
  for (int off = 1; off < 256; off <<= 1) {
    uint32_t v = (t >= off) ? tsum[t - off] : 0u;
    __syncthreads();
    tsum[t] += v;
    __syncthreads();
  }
  uint32_t run = tsum[t] - own;                       // exclusive prefix within block
#pragma unroll
  for (int j = 0; j < 4; ++j) {
    if (base + j < TOT_ROWS) offs_local[base + j] = run;
    run += c[j];
  }
  if (t == 255) blocksums[b] = tsum[255];
}

// level 2: one block scans the NSCB block sums -> exclusive block offsets
__global__ __launch_bounds__(256) void k_scan2(const uint32_t* __restrict__ blocksums,
                                               uint32_t* __restrict__ blockoffs) {
  __shared__ uint32_t s[256];
  int t = threadIdx.x;
  uint32_t v = (t < NSCB) ? blocksums[t] : 0u;
  s[t] = v;
  __syncthreads();
  uint32_t own = v;
  for (int off = 1; off < 256; off <<= 1) {
    uint32_t w = (t >= off) ? s[t - off] : 0u;
    __syncthreads();
    s[t] += w;
    __syncthreads();
  }
  if (t < NSCB) blockoffs[t] = s[t] - own;
}

// level 3: add block offset; write both offs and cursor
__global__ void k_scan3(const uint32_t* __restrict__ offs_local,
                        const uint32_t* __restrict__ blockoffs,
                        uint32_t* __restrict__ offs, uint32_t* __restrict__ cursor) {
  int t = blockIdx.x * blockDim.x + threadIdx.x;
  if (t > TOT_ROWS) return;
  uint32_t v = (t == TOT_ROWS) ? (uint32_t)(A_ADJ * E_EDGES)
                               : offs_local[t] + blockoffs[t >> 10];
  offs[t] = v;
  if (t < TOT_ROWS) cursor[t] = v;
}

__global__ void k_scatter(const int* __restrict__ rows, const int* __restrict__ cols,
                          const float* __restrict__ vals, uint32_t* __restrict__ cursor,
                          uint64_t* __restrict__ sedge) {
  int t = blockIdx.x * blockDim.x + threadIdx.x;      // over A*E
  if (t >= A_ADJ * E_EDGES) return;
  int a = t / E_EDGES;
  uint32_t pos = atomicAdd(&cursor[a * N_NODES + rows[t]], 1u);
  uint64_t packed = ((uint64_t)__float_as_uint(vals[t]) << 32) | (uint32_t)cols[t];
  sedge[pos] = packed;
}

// ---------------- SpMM over CSR: one wave per (a,row), 2-deep unroll ----------------
__global__ void k_spmm_csr(const uint32_t* __restrict__ offs,
                           const uint64_t* __restrict__ sedge,
                           const uint16_t* __restrict__ hp0,
                           float* __restrict__ stack) {
  int gw = (int)((blockIdx.x * (size_t)blockDim.x + threadIdx.x) >> 6);  // (a*N+row)
  int l = threadIdx.x & 63;
  if (gw >= TOT_ROWS) return;
  uint32_t s = offs[gw], e = offs[gw + 1];
  float a0 = 0.0f, a1 = 0.0f;
  const uint32_t* hp32 = (const uint32_t*)hp0;
  uint32_t i = s;
  for (; i + 2 <= e; i += 2) {
    uint64_t e0 = sedge[i], e1 = sedge[i + 1];
    uint32_t p0 = hp32[(size_t)(uint32_t)e0 * 64 + l];
    uint32_t p1 = hp32[(size_t)(uint32_t)e1 * 64 + l];
    float v0 = __uint_as_float((uint32_t)(e0 >> 32));
    float v1 = __uint_as_float((uint32_t)(e1 >> 32));
    a0 += bf2f((uint16_t)(p0 & 0xffffu)) * v0;
    a1 += bf2f((uint16_t)(p0 >> 16)) * v0;
    a0 += bf2f((uint16_t)(p1 & 0xffffu)) * v1;
    a1 += bf2f((uint16_t)(p1 >> 16)) * v1;
  }
  if (i < e) {
    uint64_t e0 = sedge[i];
    uint32_t p0 = hp32[(size_t)(uint32_t)e0 * 64 + l];
    float v0 = __uint_as_float((uint32_t)(e0 >> 32));
    a0 += bf2f((uint16_t)(p0 & 0xffffu)) * v0;
    a1 += bf2f((uint16_t)(p0 >> 16)) * v0;
  }
  ((float2*)stack)[(size_t)gw * 64 + l] = make_float2(a0, a1);
}

// ---------------- fusion: mean over A ----------------
__global__ void k_fusion(const float* __restrict__ stack, float* __restrict__ fus) {
  const int Q = (N_NODES * DDIM) / 4;
  int t = blockIdx.x * blockDim.x + threadIdx.x;
  if (t >= Q) return;
  const float4* s = (const float4*)stack;
  float4 s0 = s[t], s1 = s[t + Q], s2 = s[t + 2 * Q];
  float4 r;
  r.x = (s0.x + s1.x + s2.x) * (1.0f / 3.0f);
  r.y = (s0.y + s1.y + s2.y) * (1.0f / 3.0f);
  r.z = (s0.z + s1.z + s2.z) * (1.0f / 3.0f);
  r.w = (s0.w + s1.w + s2.w) * (1.0f / 3.0f);
  ((float4*)fus)[t] = r;
}

extern "C" void kernel_launch(void* const* d_in, const int* in_sizes, int n_in,
                              void* d_out, int out_size, void* d_ws, size_t ws_size,
                              hipStream_t stream) {
  const float* seq  = (const float*)d_in[0];
  const float* W1   = (const float*)d_in[1];
  const float* b1   = (const float*)d_in[2];
  const float* W2   = (const float*)d_in[3];
  const float* b2   = (const float*)d_in[4];
  const float* vals = (const float*)d_in[5];
  const int*   rows = (const int*)d_in[6];
  const int*   cols = (const int*)d_in[7];

  float* out       = (float*)d_out;
  float* out_ha    = out;                                       // [N, D]
  float* out_stack = out + (size_t)N_NODES * DDIM;              // [A, N, D]
  float* out_fus   = out_stack + (size_t)A_ADJ * N_NODES * DDIM;

  uint16_t* x   = (uint16_t*)d_ws;                              // [M_PAD, NIN] bf16
  uint16_t* h   = x   + (size_t)M_PAD * NIN;                    // [M_PAD, HDIM] bf16
  uint16_t* w1t = h   + (size_t)M_PAD * HDIM;                   // [HDIM, NIN]  bf16
  uint16_t* w2t = w1t + (size_t)HDIM * NIN;                     // [DDIM, HDIM] bf16
  uint16_t* hp0 = w2t + (size_t)DDIM * HDIM;                    // [N, D] bf16

  // CSR-build buffers alias the x region (x is dead after k_gemm<0>)
  char* xbase = (char*)d_ws;
  uint32_t* counts     = (uint32_t*)(xbase);                    // [A*N]      600KB
  uint32_t* offs       = (uint32_t*)(xbase + 640 * 1024);       // [A*N + 1]
  uint32_t* cursor     = (uint32_t*)(xbase + 1280 * 1024);      // [A*N]
  uint64_t* sedge      = (uint64_t*)(xbase + 2048 * 1024);      // [A*E] 19.2MB
  uint32_t* offs_local = (uint32_t*)(xbase + 22528 * 1024);     // [A*N]  600KB
  uint32_t* blocksums  = (uint32_t*)(xbase + 23552 * 1024);     // [NSCB]
  uint32_t* blockoffs  = (uint32_t*)(xbase + 23556 * 1024);     // [NSCB]

  // JAX partitionable-mode split of key (0,42)
  uint32_t k0a, k0b, k1a, k1b;
  threefry2x32(0u, 42u, 0u, 0u, k0a, k0b);
  threefry2x32(0u, 42u, 0u, 1u, k1a, k1b);

  k_transpose<<<(HDIM * NIN / 2 + 255) / 256, 256, 0, stream>>>(W1, w1t, NIN, HDIM);
  k_transpose<<<(HDIM * DDIM / 2 + 255) / 256, 256, 0, stream>>>(W2, w2t, HDIM, DDIM);

  k_dropin<<<((N_NODES * NIN / 4) + 255) / 256, 256, 0, stream>>>(seq, x, k0a, k0b);

  dim3 g1(HDIM / 128, M_PAD / 128);   // (4, 391)
  k_gemm<0><<<g1, 256, 0, stream>>>(x, w1t, b1, h, nullptr, HDIM, NIN);

  // ---- CSR build (x region now dead) ----
  (void)hipMemsetAsync(counts, 0, (size_t)TOT_ROWS * sizeof(uint32_t), stream);
  k_hist<<<(A_ADJ * E_EDGES + 255) / 256, 256, 0, stream>>>(rows, counts);
  k_scan1<<<NSCB, 256, 0, stream>>>(counts, offs_local, blocksums);
  k_scan2<<<1, 256, 0, stream>>>(blocksums, blockoffs);
  k_scan3<<<(TOT_ROWS + 1 + 255) / 256, 256, 0, stream>>>(offs_local, blockoffs, offs, cursor);
  k_scatter<<<(A_ADJ * E_EDGES + 255) / 256, 256, 0, stream>>>(rows, cols, vals, cursor, sedge);

  dim3 g2(DDIM / 128, M_PAD / 128);   // (1, 391)
  k_gemm<1><<<g2, 256, 0, stream>>>(h, w2t, b2, nullptr, out_ha, DDIM, HDIM);

  k_drop2<<<((N_NODES * DDIM / 4) + 255) / 256, 256, 0, stream>>>(out_ha, hp0, k1a, k1b);

  size_t csr_threads = (size_t)TOT_ROWS * 64;
  k_spmm_csr<<<(unsigned)((csr_threads + 255) / 256), 256, 0, stream>>>(offs, sedge, hp0, out_stack);

  k_fusion<<<((N_NODES * DDIM / 4) + 255) / 256, 256, 0, stream>>>(out_stack, out_fus);
}